// Round 12
// baseline (367.967 us; speedup 1.0000x reference)
//
#include <hip/hip_runtime.h>

#define N_USERS 100000
#define N_ITEMS 40000
#define NN      140000          // N_NODES
#define N_EDGES 1000000
#define ALPHA   0.2f

typedef short bf16x8 __attribute__((ext_vector_type(8)));
typedef float f32x4  __attribute__((ext_vector_type(4)));

__device__ __forceinline__ unsigned short f2b(float x) {
    unsigned u = __builtin_bit_cast(unsigned, x);
    unsigned r = (u + 0x7FFFu + ((u >> 16) & 1u)) >> 16;
    return (unsigned short)r;
}
__device__ __forceinline__ unsigned cvtpk(float lo, float hi) {   // 2xf32 -> packed bf16 (RNE)
    unsigned r;
    asm("v_cvt_pk_bf16_f32 %0, %1, %2" : "=v"(r) : "v"(lo), "v"(hi));
    return r;
}
__device__ __forceinline__ float blo(unsigned u) { return __builtin_bit_cast(float, u << 16); }
__device__ __forceinline__ float bhi(unsigned u) { return __builtin_bit_cast(float, u & 0xFFFF0000u); }

// ---------------------------------------------------------------------------
// prep: block-range fused  [copy_pref | conv_w(img) | conv_w(txt) | hist]
#define PREP_CP   6250
#define PREP_CI   (PREP_CP + 512)
#define PREP_CT   (PREP_CI + 96)
#define PREP_ALL  (PREP_CT + 3907)

__global__ __launch_bounds__(256)
void prep(const float* __restrict__ imgp, const float* __restrict__ txtp,
          unsigned short* __restrict__ X,
          const float* __restrict__ Wi, short* __restrict__ WtImg,
          const float* __restrict__ Wx, short* __restrict__ WtTxt,
          const int* __restrict__ ei, int* __restrict__ deg)
{
    int b = blockIdx.x, t = threadIdx.x;
    if (b < PREP_CP) {
        int tid = b * 256 + t;                   // N_USERS*16 8-dim chunks
        if (tid >= N_USERS * 16) return;
        int i  = tid >> 4;
        int c8 = tid & 15;
        const float* src = (c8 < 8) ? &imgp[(size_t)i * 64 + c8 * 8]
                                    : &txtp[(size_t)i * 64 + (c8 - 8) * 8];
        float4 a = *reinterpret_cast<const float4*>(src);
        float4 c = *reinterpret_cast<const float4*>(src + 4);
        int4 o = make_int4((int)cvtpk(a.x, a.y), (int)cvtpk(a.z, a.w),
                           (int)cvtpk(c.x, c.y), (int)cvtpk(c.z, c.w));
        *reinterpret_cast<int4*>(&X[(size_t)i * 128 + c8 * 8]) = o;
    } else if (b < PREP_CI) {
        int tid = (b - PREP_CP) * 256 + t;       // 2048*64
        int k = tid >> 6, n = tid & 63;
        WtImg[(k >> 5) * 2048 + n * 32 + ((k >> 3) & 3) * 8 + (k & 7)] = (short)f2b(Wi[tid]);
    } else if (b < PREP_CT) {
        int tid = (b - PREP_CI) * 256 + t;       // 384*64
        if (tid >= 384 * 64) return;
        int k = tid >> 6, n = tid & 63;
        WtTxt[(k >> 5) * 2048 + n * 32 + ((k >> 3) & 3) * 8 + (k & 7)] = (short)f2b(Wx[tid]);
    } else {
        int e = (b - PREP_CT) * 256 + t;
        if (e < N_EDGES) atomicAdd(&deg[ei[N_EDGES + e]], 1);
    }
}

// ---------------------------------------------------------------------------
// MFMA GEMM + bias + L2-normalize, LDS-free.
// 2 waves/block; each wave owns 32 rows as TWO 16-row row-blocks sharing B.
// 2-deep ping-pong; asm memory clobbers pin the prefetch loads above compute
// (compiler was sinking them -> single-buffer serialization, VGPR=64).
template<int K, int COLOFF>
__device__ __forceinline__
void gemm_body(int bx, const float* __restrict__ A, const short* __restrict__ Wt,
               const float* __restrict__ bias, unsigned short* __restrict__ X)
{
    constexpr int STEPS = K / 32;     // 64 (img) / 12 (txt), both even
    const int t    = threadIdx.x;     // 0..127
    const int wid  = t >> 6;          // 0..1
    const int lane = t & 63;
    const int lo   = lane & 15;
    const int g    = lane >> 4;
    const int r0   = bx * 64 + wid * 32;

    const float* Ap0 = A + (size_t)(r0 + lo) * K + g * 8;
    const float* Ap1 = A + (size_t)(r0 + 16 + lo) * K + g * 8;
    const short* Bp0 = Wt + lo * 32 + g * 8;

    f32x4 acc0[4], acc1[4];
    #pragma unroll
    for (int ct = 0; ct < 4; ++ct) {
        acc0[ct] = (f32x4){0.f, 0.f, 0.f, 0.f};
        acc1[ct] = (f32x4){0.f, 0.f, 0.f, 0.f};
    }

    float4 x0A, y0A, x0B, y0B, x1A, y1A, x1B, y1B;
    bf16x8 bA[4], bB[4];

    auto loadA = [&](const float* Ap, int s, float4& x, float4& y) {
        const float* p = Ap + s * 32;
        x = *reinterpret_cast<const float4*>(p);
        y = *reinterpret_cast<const float4*>(p + 4);
    };
    auto loadB = [&](int s, bf16x8* bb) {
        const short* p = Bp0 + s * 2048;
        #pragma unroll
        for (int ct = 0; ct < 4; ++ct) {
            int4 w = *reinterpret_cast<const int4*>(p + ct * 512);
            bb[ct] = __builtin_bit_cast(bf16x8, w);
        }
    };
    auto domfma = [&](f32x4* acc, const float4& x, const float4& y, const bf16x8* bb) {
        int4 ai = make_int4((int)cvtpk(x.x, x.y), (int)cvtpk(x.z, x.w),
                            (int)cvtpk(y.x, y.y), (int)cvtpk(y.z, y.w));
        bf16x8 a = __builtin_bit_cast(bf16x8, ai);
        #pragma unroll
        for (int ct = 0; ct < 4; ++ct)
            acc[ct] = __builtin_amdgcn_mfma_f32_16x16x32_bf16(a, bb[ct], acc[ct], 0, 0, 0);
    };

    loadA(Ap0, 0, x0A, y0A);
    loadA(Ap1, 0, x1A, y1A);
    loadB(0, bA);
    for (int s = 0; s < STEPS; s += 2) {
        loadA(Ap0, s + 1, x0B, y0B);          // prefetch next (STEPS even)
        loadA(Ap1, s + 1, x1B, y1B);
        loadB(s + 1, bB);
        asm volatile("" ::: "memory");        // pin prefetch above compute
        domfma(acc0, x0A, y0A, bA);
        domfma(acc1, x1A, y1A, bA);
        if (s + 2 < STEPS) {
            loadA(Ap0, s + 2, x0A, y0A);
            loadA(Ap1, s + 2, x1A, y1A);
            loadB(s + 2, bA);
        }
        asm volatile("" ::: "memory");        // pin prefetch above compute
        domfma(acc0, x0B, y0B, bB);
        domfma(acc1, x1B, y1B, bB);
    }

    float bia[4];
    #pragma unroll
    for (int ct = 0; ct < 4; ++ct) bia[ct] = bias[ct * 16 + lo];

    #pragma unroll
    for (int rb = 0; rb < 2; ++rb) {
        f32x4* acc = rb ? acc1 : acc0;
        int rbase = r0 + rb * 16;
        #pragma unroll
        for (int r = 0; r < 4; ++r) {
            float v[4];
            float ss = 0.f;
            #pragma unroll
            for (int ct = 0; ct < 4; ++ct) { v[ct] = acc[ct][r] + bia[ct]; ss += v[ct] * v[ct]; }
            ss += __shfl_xor(ss, 1);
            ss += __shfl_xor(ss, 2);
            ss += __shfl_xor(ss, 4);
            ss += __shfl_xor(ss, 8);
            float sc = 1.0f / fmaxf(sqrtf(ss), 1e-12f);
            int grow = rbase + g * 4 + r;
            unsigned short* dst = &X[(size_t)(N_USERS + grow) * 128 + COLOFF + lo];
            #pragma unroll
            for (int ct = 0; ct < 4; ++ct) dst[ct * 16] = f2b(v[ct] * sc);
        }
    }
}

__global__ __launch_bounds__(128, 1)
void gemm_both(const float* __restrict__ Ai, const short* __restrict__ WtImg,
               const float* __restrict__ bi,
               const float* __restrict__ Ax, const short* __restrict__ WtTxt,
               const float* __restrict__ bx, unsigned short* __restrict__ X)
{
    int b = blockIdx.x;
    if (b < 625) gemm_body<2048, 0 >(b, Ai, WtImg, bi, X);
    else         gemm_body< 384, 64>(b - 625, Ax, WtTxt, bx, X);
}

// ---------------------------------------------------------------------------
// CSR scans
__global__ void scan1(const int* __restrict__ deg, int* __restrict__ row_ptr,
                      int* __restrict__ blockSums)
{
    __shared__ int ts[256];
    int t = threadIdx.x, b = blockIdx.x;
    int base = b * 1024 + t * 4;
    int v[4]; int s = 0;
    #pragma unroll
    for (int j = 0; j < 4; j++) {
        v[j] = (base + j < NN) ? deg[base + j] : 0;
        s += v[j];
    }
    ts[t] = s;
    __syncthreads();
    for (int off = 1; off < 256; off <<= 1) {
        int x = (t >= off) ? ts[t - off] : 0;
        __syncthreads();
        ts[t] += x;
        __syncthreads();
    }
    int excl = ts[t] - s;
    int run = excl;
    #pragma unroll
    for (int j = 0; j < 4; j++) {
        if (base + j < NN) row_ptr[base + j] = run;
        run += v[j];
    }
    if (t == 255) blockSums[b] = ts[255];
}

// merged scan2+scan3: each block re-reduces blockSums[0..b-1] (137 entries, cheap)
__global__ void scan23(const int* __restrict__ blockSums, int* __restrict__ row_ptr,
                       int* __restrict__ cursor)
{
    __shared__ int ts[256];
    int t = threadIdx.x, b = blockIdx.x;
    ts[t] = (t < b) ? blockSums[t] : 0;     // b <= 136 < 256
    __syncthreads();
    for (int off = 128; off > 0; off >>= 1) {
        if (t < off) ts[t] += ts[t + off];
        __syncthreads();
    }
    int off0 = ts[0];
    int base = b * 1024 + t * 4;
    #pragma unroll
    for (int j = 0; j < 4; j++) {
        int idx = base + j;
        if (idx < NN) {
            int r = row_ptr[idx] + off0;
            row_ptr[idx] = r;
            cursor[idx]  = r;
        }
    }
    if (b == 0 && t == 0) row_ptr[NN] = N_EDGES;
}

__global__ void fill_kernel(const int* __restrict__ ei, const float* __restrict__ ew,
                            int* __restrict__ cursor, int2* __restrict__ epk)
{
    int e = blockIdx.x * 256 + threadIdx.x;
    if (e >= N_EDGES) return;
    int s = ei[e];
    int d = ei[N_EDGES + e];
    int p = atomicAdd(&cursor[d], 1);
    epk[p] = make_int2(s, __builtin_bit_cast(int, ew[e]));
}

// ---------------------------------------------------------------------------
// Propagation: one wave per node, lane owns 2 of 128 dims (one u32).
// Edge (src,w) batch-loaded 64/wave as int2, broadcast via shfl.
// FINAL=true writes f32 split [2][NN][64] output.
template<bool FINAL>
__global__ __launch_bounds__(256)
void propagate(const unsigned short* __restrict__ Xin, const int* __restrict__ row_ptr,
               const int2* __restrict__ epk, void* __restrict__ outv)
{
    int wid  = threadIdx.x >> 6;
    int lane = threadIdx.x & 63;
    int node = blockIdx.x * 4 + wid;
    if (node >= NN) return;
    int e0 = row_ptr[node];
    int e1 = row_ptr[node + 1];
    float accx = 0.f, accy = 0.f;
    for (int base = e0; base < e1; base += 64) {
        int cnt = e1 - base; if (cnt > 64) cnt = 64;
        int sv = 0, wvb = 0;
        if (base + lane < e1) {
            int2 ev = epk[base + lane];
            sv = ev.x; wvb = ev.y;
        }
        float wv = __builtin_bit_cast(float, wvb);
        int i = 0;
        for (; i + 3 < cnt; i += 4) {
            int   s0 = __shfl(sv, i),     s1 = __shfl(sv, i + 1);
            int   s2 = __shfl(sv, i + 2), s3 = __shfl(sv, i + 3);
            float w0 = __shfl(wv, i),     w1 = __shfl(wv, i + 1);
            float w2 = __shfl(wv, i + 2), w3 = __shfl(wv, i + 3);
            unsigned u0 = *reinterpret_cast<const unsigned*>(&Xin[(size_t)s0 * 128 + lane * 2]);
            unsigned u1 = *reinterpret_cast<const unsigned*>(&Xin[(size_t)s1 * 128 + lane * 2]);
            unsigned u2 = *reinterpret_cast<const unsigned*>(&Xin[(size_t)s2 * 128 + lane * 2]);
            unsigned u3 = *reinterpret_cast<const unsigned*>(&Xin[(size_t)s3 * 128 + lane * 2]);
            accx = fmaf(w0, blo(u0), accx); accy = fmaf(w0, bhi(u0), accy);
            accx = fmaf(w1, blo(u1), accx); accy = fmaf(w1, bhi(u1), accy);
            accx = fmaf(w2, blo(u2), accx); accy = fmaf(w2, bhi(u2), accy);
            accx = fmaf(w3, blo(u3), accx); accy = fmaf(w3, bhi(u3), accy);
        }
        for (; i < cnt; ++i) {
            int   s0 = __shfl(sv, i);
            float w0 = __shfl(wv, i);
            unsigned u0 = *reinterpret_cast<const unsigned*>(&Xin[(size_t)s0 * 128 + lane * 2]);
            accx = fmaf(w0, blo(u0), accx); accy = fmaf(w0, bhi(u0), accy);
        }
    }
    unsigned us = *reinterpret_cast<const unsigned*>(&Xin[(size_t)node * 128 + lane * 2]);
    accx += ALPHA * blo(us);
    accy += ALPHA * bhi(us);
    if (!FINAL) {
        unsigned short* out = (unsigned short*)outv;
        *reinterpret_cast<unsigned*>(&out[(size_t)node * 128 + lane * 2]) = cvtpk(accx, accy);
    } else {
        float* out = (float*)outv;
        int d = lane * 2;
        float* dst = (d < 64) ? &out[(size_t)node * 64 + d]
                              : &out[(size_t)NN * 64 + (size_t)node * 64 + (d - 64)];
        *reinterpret_cast<float2*>(dst) = make_float2(accx, accy);
    }
}

// ---------------------------------------------------------------------------
extern "C" void kernel_launch(void* const* d_in, const int* in_sizes, int n_in,
                              void* d_out, int out_size, void* d_ws, size_t ws_size,
                              hipStream_t stream)
{
    const int*   ei       = (const int*)d_in[0];
    const float* ew       = (const float*)d_in[1];
    const float* img_feat = (const float*)d_in[2];
    const float* txt_feat = (const float*)d_in[3];
    const float* img_w    = (const float*)d_in[4];
    const float* img_b    = (const float*)d_in[5];
    const float* txt_w    = (const float*)d_in[6];
    const float* txt_b    = (const float*)d_in[7];
    const float* img_pref = (const float*)d_in[8];
    const float* txt_pref = (const float*)d_in[9];
    float* out = (float*)d_out;

    const size_t XBYTES = (size_t)NN * 128 * 2;      // bf16
    char* ws = (char*)d_ws;
    size_t off = 0;
    auto alloc = [&](size_t bytes) -> void* {
        void* p = ws + off;
        off = (off + bytes + 255) & ~(size_t)255;
        return p;
    };
    unsigned short* Xa = (unsigned short*)alloc(XBYTES);
    unsigned short* Xb = (unsigned short*)alloc(XBYTES);
    int*   deg     = (int*)alloc((size_t)NN * 4);
    int*   row_ptr = (int*)alloc((size_t)(NN + 1) * 4);
    int*   cursor  = (int*)alloc((size_t)NN * 4);
    int2*  epk     = (int2*)alloc((size_t)N_EDGES * 8);
    int*   bsums   = (int*)alloc(256 * 4);
    short* WtImg   = (short*)alloc((size_t)2048 * 64 * 2);
    short* WtTxt   = (short*)alloc((size_t)384 * 64 * 2);

    hipMemsetAsync(deg, 0, (size_t)NN * 4, stream);

    prep<<<PREP_ALL, 256, 0, stream>>>(img_pref, txt_pref, Xa,
                                       img_w, WtImg, txt_w, WtTxt, ei, deg);

    scan1<<<137, 256, 0, stream>>>(deg, row_ptr, bsums);
    scan23<<<137, 256, 0, stream>>>(bsums, row_ptr, cursor);

    gemm_both<<<1250, 128, 0, stream>>>(img_feat, WtImg, img_b,
                                        txt_feat, WtTxt, txt_b, Xa);

    fill_kernel<<<3907, 256, 0, stream>>>(ei, ew, cursor, epk);

    propagate<false><<<35000, 256, 0, stream>>>(Xa, row_ptr, epk, Xb);
    propagate<true ><<<35000, 256, 0, stream>>>(Xb, row_ptr, epk, out);
}

// Round 13
// 326.621 us; speedup vs baseline: 1.1266x; 1.1266x over previous
//
#include <hip/hip_runtime.h>

#define N_USERS 100000
#define N_ITEMS 40000
#define NN      140000          // N_NODES
#define N_EDGES 1000000
#define ALPHA   0.2f

typedef short bf16x8 __attribute__((ext_vector_type(8)));
typedef float f32x4  __attribute__((ext_vector_type(4)));

__device__ __forceinline__ unsigned short f2b(float x) {
    unsigned u = __builtin_bit_cast(unsigned, x);
    unsigned r = (u + 0x7FFFu + ((u >> 16) & 1u)) >> 16;
    return (unsigned short)r;
}
__device__ __forceinline__ unsigned cvtpk(float lo, float hi) {   // 2xf32 -> packed bf16 (RNE)
    unsigned r;
    asm("v_cvt_pk_bf16_f32 %0, %1, %2" : "=v"(r) : "v"(lo), "v"(hi));
    return r;
}
__device__ __forceinline__ float blo(unsigned u) { return __builtin_bit_cast(float, u << 16); }
__device__ __forceinline__ float bhi(unsigned u) { return __builtin_bit_cast(float, u & 0xFFFF0000u); }

// async global->LDS, 16B per lane; dest = wave-uniform base + lane*16 (HW rule)
__device__ __forceinline__ void gl_lds16(const float* g, float* l) {
    __builtin_amdgcn_global_load_lds(
        (const __attribute__((address_space(1))) void*)g,
        (__attribute__((address_space(3))) void*)l, 16, 0, 0);
}

// ---------------------------------------------------------------------------
// prep: block-range fused  [copy_pref | conv_w(img) | conv_w(txt) | hist]
#define PREP_CP   6250
#define PREP_CI   (PREP_CP + 512)
#define PREP_CT   (PREP_CI + 96)
#define PREP_ALL  (PREP_CT + 3907)

__global__ __launch_bounds__(256)
void prep(const float* __restrict__ imgp, const float* __restrict__ txtp,
          unsigned short* __restrict__ X,
          const float* __restrict__ Wi, short* __restrict__ WtImg,
          const float* __restrict__ Wx, short* __restrict__ WtTxt,
          const int* __restrict__ ei, int* __restrict__ deg)
{
    int b = blockIdx.x, t = threadIdx.x;
    if (b < PREP_CP) {
        int tid = b * 256 + t;                   // N_USERS*16 8-dim chunks
        if (tid >= N_USERS * 16) return;
        int i  = tid >> 4;
        int c8 = tid & 15;
        const float* src = (c8 < 8) ? &imgp[(size_t)i * 64 + c8 * 8]
                                    : &txtp[(size_t)i * 64 + (c8 - 8) * 8];
        float4 a = *reinterpret_cast<const float4*>(src);
        float4 c = *reinterpret_cast<const float4*>(src + 4);
        int4 o = make_int4((int)cvtpk(a.x, a.y), (int)cvtpk(a.z, a.w),
                           (int)cvtpk(c.x, c.y), (int)cvtpk(c.z, c.w));
        *reinterpret_cast<int4*>(&X[(size_t)i * 128 + c8 * 8]) = o;
    } else if (b < PREP_CI) {
        int tid = (b - PREP_CP) * 256 + t;       // 2048*64
        int k = tid >> 6, n = tid & 63;
        WtImg[(k >> 5) * 2048 + n * 32 + ((k >> 3) & 3) * 8 + (k & 7)] = (short)f2b(Wi[tid]);
    } else if (b < PREP_CT) {
        int tid = (b - PREP_CI) * 256 + t;       // 384*64
        if (tid >= 384 * 64) return;
        int k = tid >> 6, n = tid & 63;
        WtTxt[(k >> 5) * 2048 + n * 32 + ((k >> 3) & 3) * 8 + (k & 7)] = (short)f2b(Wx[tid]);
    } else {
        int e = (b - PREP_CT) * 256 + t;
        if (e < N_EDGES) atomicAdd(&deg[ei[N_EDGES + e]], 1);
    }
}

// ---------------------------------------------------------------------------
// MFMA GEMM, m97-style: A staged via global_load_lds into double-buffered LDS
// (64 rows x 64 k f32 per tile, 16KB x2), XOR-swizzled 16B units (both sides).
// 4 waves/block, each wave = 16 rows x 64 cols. B frags from L2-resident Wt.
template<int K, int COLOFF>
__device__ __forceinline__
void gemm_body(int bx, const float* __restrict__ A, const short* __restrict__ Wt,
               const float* __restrict__ bias, unsigned short* __restrict__ X,
               float* lds)
{
    constexpr int NT = K / 64;        // tiles: img 32, txt 6
    const int t    = threadIdx.x;     // 0..255
    const int wid  = t >> 6;
    const int lane = t & 63;
    const int lo   = lane & 15;
    const int g    = lane >> 4;
    const int r0   = bx * 64;

    const short* Bp0 = Wt + lo * 32 + g * 8;

    f32x4 acc[4];
    #pragma unroll
    for (int ct = 0; ct < 4; ++ct) acc[ct] = (f32x4){0.f, 0.f, 0.f, 0.f};

    // stage one 64x64 tile: 4 insts/thread; inst i covers chunk c = i*4+wid
    // (1KB = 4 rows). lane: row = 4c + (lane>>4), phys unit = lane&15,
    // global unit = phys ^ (row & 15)   [XOR swizzle, involution]
    auto stage = [&](int buf, int kt) {
        int k0 = kt * 64;
        #pragma unroll
        for (int i = 0; i < 4; ++i) {
            int c     = i * 4 + wid;
            int row_t = c * 4 + g;                 // this lane's row (0..63)
            int u_log = lo ^ (row_t & 15);
            const float* gp = A + (size_t)(r0 + row_t) * K + k0 + u_log * 4;
            gl_lds16(gp, lds + buf * 4096 + c * 256);
        }
    };

    // compute one tile: 2 MFMA k-steps (K=32 each)
    auto compute = [&](int buf, int kt) {
        int row_t = wid * 16 + lo;
        const float* base = lds + buf * 4096 + row_t * 64;
        #pragma unroll
        for (int m = 0; m < 2; ++m) {
            int u0 = (m * 8 + 2 * g) ^ lo;         // swizzled read
            int u1 = (m * 8 + 2 * g + 1) ^ lo;
            float4 xa = *reinterpret_cast<const float4*>(base + u0 * 4);
            float4 ya = *reinterpret_cast<const float4*>(base + u1 * 4);
            int4 ai = make_int4((int)cvtpk(xa.x, xa.y), (int)cvtpk(xa.z, xa.w),
                                (int)cvtpk(ya.x, ya.y), (int)cvtpk(ya.z, ya.w));
            bf16x8 a = __builtin_bit_cast(bf16x8, ai);
            const short* p = Bp0 + (size_t)(kt * 2 + m) * 2048;
            #pragma unroll
            for (int ct = 0; ct < 4; ++ct) {
                int4 w = *reinterpret_cast<const int4*>(p + ct * 512);
                bf16x8 bb = __builtin_bit_cast(bf16x8, w);
                acc[ct] = __builtin_amdgcn_mfma_f32_16x16x32_bf16(a, bb, acc[ct], 0, 0, 0);
            }
        }
    };

    stage(0, 0);
    __syncthreads();                   // staged tile 0 ready (drains vmcnt)
    for (int kt = 0; kt < NT; ++kt) {
        if (kt + 1 < NT) stage((kt + 1) & 1, kt + 1);   // async, overlaps compute
        compute(kt & 1, kt);
        __syncthreads();               // next buf ready + all reads of cur done
    }

    float bia[4];
    #pragma unroll
    for (int ct = 0; ct < 4; ++ct) bia[ct] = bias[ct * 16 + lo];

    int r0w = r0 + wid * 16;
    #pragma unroll
    for (int r = 0; r < 4; ++r) {
        float v[4];
        float ss = 0.f;
        #pragma unroll
        for (int ct = 0; ct < 4; ++ct) { v[ct] = acc[ct][r] + bia[ct]; ss += v[ct] * v[ct]; }
        ss += __shfl_xor(ss, 1);
        ss += __shfl_xor(ss, 2);
        ss += __shfl_xor(ss, 4);
        ss += __shfl_xor(ss, 8);
        float sc = 1.0f / fmaxf(sqrtf(ss), 1e-12f);
        int grow = r0w + g * 4 + r;
        unsigned short* dst = &X[(size_t)(N_USERS + grow) * 128 + COLOFF + lo];
        #pragma unroll
        for (int ct = 0; ct < 4; ++ct) dst[ct * 16] = f2b(v[ct] * sc);
    }
}

// Fused: blocks 0..624 img GEMM, 625..1249 txt GEMM, 1250.. fill (CSR scatter)
__global__ __launch_bounds__(256)
void gemm_fill(const float* __restrict__ Ai, const short* __restrict__ WtImg,
               const float* __restrict__ bi,
               const float* __restrict__ Ax, const short* __restrict__ WtTxt,
               const float* __restrict__ bx, unsigned short* __restrict__ X,
               const int* __restrict__ ei, const float* __restrict__ ew,
               int* __restrict__ cursor, int2* __restrict__ epk)
{
    __shared__ float lds[8192];        // 2 x (64 rows x 64 k) f32 = 32KB
    int b = blockIdx.x;
    if (b < 625)       gemm_body<2048, 0 >(b, Ai, WtImg, bi, X, lds);
    else if (b < 1250) gemm_body< 384, 64>(b - 625, Ax, WtTxt, bx, X, lds);
    else {
        int e = (b - 1250) * 256 + threadIdx.x;
        if (e >= N_EDGES) return;
        int s = ei[e];
        int d = ei[N_EDGES + e];
        int p = atomicAdd(&cursor[d], 1);
        epk[p] = make_int2(s, __builtin_bit_cast(int, ew[e]));
    }
}

// ---------------------------------------------------------------------------
// CSR scans
__global__ void scan1(const int* __restrict__ deg, int* __restrict__ row_ptr,
                      int* __restrict__ blockSums)
{
    __shared__ int ts[256];
    int t = threadIdx.x, b = blockIdx.x;
    int base = b * 1024 + t * 4;
    int v[4]; int s = 0;
    #pragma unroll
    for (int j = 0; j < 4; j++) {
        v[j] = (base + j < NN) ? deg[base + j] : 0;
        s += v[j];
    }
    ts[t] = s;
    __syncthreads();
    for (int off = 1; off < 256; off <<= 1) {
        int x = (t >= off) ? ts[t - off] : 0;
        __syncthreads();
        ts[t] += x;
        __syncthreads();
    }
    int excl = ts[t] - s;
    int run = excl;
    #pragma unroll
    for (int j = 0; j < 4; j++) {
        if (base + j < NN) row_ptr[base + j] = run;
        run += v[j];
    }
    if (t == 255) blockSums[b] = ts[255];
}

// merged scan2+scan3: each block re-reduces blockSums[0..b-1] (137 entries, cheap)
__global__ void scan23(const int* __restrict__ blockSums, int* __restrict__ row_ptr,
                       int* __restrict__ cursor)
{
    __shared__ int ts[256];
    int t = threadIdx.x, b = blockIdx.x;
    ts[t] = (t < b) ? blockSums[t] : 0;     // b <= 136 < 256
    __syncthreads();
    for (int off = 128; off > 0; off >>= 1) {
        if (t < off) ts[t] += ts[t + off];
        __syncthreads();
    }
    int off0 = ts[0];
    int base = b * 1024 + t * 4;
    #pragma unroll
    for (int j = 0; j < 4; j++) {
        int idx = base + j;
        if (idx < NN) {
            int r = row_ptr[idx] + off0;
            row_ptr[idx] = r;
            cursor[idx]  = r;
        }
    }
    if (b == 0 && t == 0) row_ptr[NN] = N_EDGES;
}

// ---------------------------------------------------------------------------
// Propagation: one wave per node, lane owns 2 of 128 dims (one u32).
// Edge (src,w) batch-loaded 64/wave as int2, broadcast via shfl.
// FINAL=true writes f32 split [2][NN][64] output.
template<bool FINAL>
__global__ __launch_bounds__(256)
void propagate(const unsigned short* __restrict__ Xin, const int* __restrict__ row_ptr,
               const int2* __restrict__ epk, void* __restrict__ outv)
{
    int wid  = threadIdx.x >> 6;
    int lane = threadIdx.x & 63;
    int node = blockIdx.x * 4 + wid;
    if (node >= NN) return;
    int e0 = row_ptr[node];
    int e1 = row_ptr[node + 1];
    float accx = 0.f, accy = 0.f;
    for (int base = e0; base < e1; base += 64) {
        int cnt = e1 - base; if (cnt > 64) cnt = 64;
        int sv = 0, wvb = 0;
        if (base + lane < e1) {
            int2 ev = epk[base + lane];
            sv = ev.x; wvb = ev.y;
        }
        float wv = __builtin_bit_cast(float, wvb);
        int i = 0;
        for (; i + 3 < cnt; i += 4) {
            int   s0 = __shfl(sv, i),     s1 = __shfl(sv, i + 1);
            int   s2 = __shfl(sv, i + 2), s3 = __shfl(sv, i + 3);
            float w0 = __shfl(wv, i),     w1 = __shfl(wv, i + 1);
            float w2 = __shfl(wv, i + 2), w3 = __shfl(wv, i + 3);
            unsigned u0 = *reinterpret_cast<const unsigned*>(&Xin[(size_t)s0 * 128 + lane * 2]);
            unsigned u1 = *reinterpret_cast<const unsigned*>(&Xin[(size_t)s1 * 128 + lane * 2]);
            unsigned u2 = *reinterpret_cast<const unsigned*>(&Xin[(size_t)s2 * 128 + lane * 2]);
            unsigned u3 = *reinterpret_cast<const unsigned*>(&Xin[(size_t)s3 * 128 + lane * 2]);
            accx = fmaf(w0, blo(u0), accx); accy = fmaf(w0, bhi(u0), accy);
            accx = fmaf(w1, blo(u1), accx); accy = fmaf(w1, bhi(u1), accy);
            accx = fmaf(w2, blo(u2), accx); accy = fmaf(w2, bhi(u2), accy);
            accx = fmaf(w3, blo(u3), accx); accy = fmaf(w3, bhi(u3), accy);
        }
        for (; i < cnt; ++i) {
            int   s0 = __shfl(sv, i);
            float w0 = __shfl(wv, i);
            unsigned u0 = *reinterpret_cast<const unsigned*>(&Xin[(size_t)s0 * 128 + lane * 2]);
            accx = fmaf(w0, blo(u0), accx); accy = fmaf(w0, bhi(u0), accy);
        }
    }
    unsigned us = *reinterpret_cast<const unsigned*>(&Xin[(size_t)node * 128 + lane * 2]);
    accx += ALPHA * blo(us);
    accy += ALPHA * bhi(us);
    if (!FINAL) {
        unsigned short* out = (unsigned short*)outv;
        *reinterpret_cast<unsigned*>(&out[(size_t)node * 128 + lane * 2]) = cvtpk(accx, accy);
    } else {
        float* out = (float*)outv;
        int d = lane * 2;
        float* dst = (d < 64) ? &out[(size_t)node * 64 + d]
                              : &out[(size_t)NN * 64 + (size_t)node * 64 + (d - 64)];
        *reinterpret_cast<float2*>(dst) = make_float2(accx, accy);
    }
}

// ---------------------------------------------------------------------------
extern "C" void kernel_launch(void* const* d_in, const int* in_sizes, int n_in,
                              void* d_out, int out_size, void* d_ws, size_t ws_size,
                              hipStream_t stream)
{
    const int*   ei       = (const int*)d_in[0];
    const float* ew       = (const float*)d_in[1];
    const float* img_feat = (const float*)d_in[2];
    const float* txt_feat = (const float*)d_in[3];
    const float* img_w    = (const float*)d_in[4];
    const float* img_b    = (const float*)d_in[5];
    const float* txt_w    = (const float*)d_in[6];
    const float* txt_b    = (const float*)d_in[7];
    const float* img_pref = (const float*)d_in[8];
    const float* txt_pref = (const float*)d_in[9];
    float* out = (float*)d_out;

    const size_t XBYTES = (size_t)NN * 128 * 2;      // bf16
    char* ws = (char*)d_ws;
    size_t off = 0;
    auto alloc = [&](size_t bytes) -> void* {
        void* p = ws + off;
        off = (off + bytes + 255) & ~(size_t)255;
        return p;
    };
    unsigned short* Xa = (unsigned short*)alloc(XBYTES);
    unsigned short* Xb = (unsigned short*)alloc(XBYTES);
    int*   deg     = (int*)alloc((size_t)NN * 4);
    int*   row_ptr = (int*)alloc((size_t)(NN + 1) * 4);
    int*   cursor  = (int*)alloc((size_t)NN * 4);
    int2*  epk     = (int2*)alloc((size_t)N_EDGES * 8);
    int*   bsums   = (int*)alloc(256 * 4);
    short* WtImg   = (short*)alloc((size_t)2048 * 64 * 2);
    short* WtTxt   = (short*)alloc((size_t)384 * 64 * 2);

    hipMemsetAsync(deg, 0, (size_t)NN * 4, stream);

    prep<<<PREP_ALL, 256, 0, stream>>>(img_pref, txt_pref, Xa,
                                       img_w, WtImg, txt_w, WtTxt, ei, deg);

    scan1<<<137, 256, 0, stream>>>(deg, row_ptr, bsums);
    scan23<<<137, 256, 0, stream>>>(bsums, row_ptr, cursor);

    gemm_fill<<<1250 + 3907, 256, 0, stream>>>(img_feat, WtImg, img_b,
                                               txt_feat, WtTxt, txt_b, Xa,
                                               ei, ew, cursor, epk);

    propagate<false><<<35000, 256, 0, stream>>>(Xa, row_ptr, epk, Xb);
    propagate<true ><<<35000, 256, 0, stream>>>(Xb, row_ptr, epk, out);
}